// Round 1
// baseline (2607.145 us; speedup 1.0000x reference)
//
#include <hip/hip_runtime.h>
#include <hip/hip_bf16.h>

#define H 64

__device__ __forceinline__ float lane_bcast(float v, int k) {
    return __int_as_float(__builtin_amdgcn_readlane(__float_as_int(v), k));
}

// ---------------- degree count (once per call; edge list is round-invariant) ----
__global__ __launch_bounds__(256) void deg_count(const int* __restrict__ row,
                                                 int* __restrict__ deg, int E) {
    int e = blockIdx.x * 256 + threadIdx.x;
    if (e < E) atomicAdd(&deg[row[e]], 1);
}

// ---------------- per-node transform: xd = Wd*x_n ; agg = deg*(Ws*x_n + b) -----
// msg_W layout: [64 rows][129 cols]; cols 0..63 -> dest (x[col]), 64..127 -> src
// (x[row]), col 128 -> edge_attr coeff.
#define TNPW 8   // nodes per wave
__global__ __launch_bounds__(256) void node_transform(
    const float* __restrict__ x, const float* __restrict__ W,
    const float* __restrict__ b, const int* __restrict__ deg,
    float* __restrict__ xd, float* __restrict__ agg, int N)
{
    __shared__ float Wd[64 * 65];   // [k][j], pad 65 -> conflict-free both ways
    __shared__ float Ws[64 * 65];
    const int tid = threadIdx.x, lane = tid & 63, wv = tid >> 6;

    for (int l = tid; l < 64 * 64; l += 256) {
        int k = l & 63, j = l >> 6;
        Wd[k * 65 + j] = W[j * 129 + k];
        Ws[k * 65 + j] = W[j * 129 + 64 + k];
    }
    __syncthreads();

    const int base = (blockIdx.x * 4 + wv) * TNPW;
    float xv[TNPW], ad[TNPW], as_[TNPW];
    const float bj = b[lane];
#pragma unroll
    for (int i = 0; i < TNPW; i++) {
        int n = base + i;
        xv[i] = (n < N) ? x[(size_t)n * H + lane] : 0.f;
        ad[i] = 0.f; as_[i] = 0.f;
    }
#pragma unroll 4
    for (int k = 0; k < 64; k++) {
        float wd = Wd[k * 65 + lane];
        float ws = Ws[k * 65 + lane];
#pragma unroll
        for (int i = 0; i < TNPW; i++) {
            float xk = lane_bcast(xv[i], k);
            ad[i]  = fmaf(wd, xk, ad[i]);
            as_[i] = fmaf(ws, xk, as_[i]);
        }
    }
#pragma unroll
    for (int i = 0; i < TNPW; i++) {
        int n = base + i;
        if (n < N) {
            xd[(size_t)n * H + lane]  = ad[i];
            agg[(size_t)n * H + lane] = (float)deg[n] * (as_[i] + bj);
        }
    }
}

// ---------------- edge scatter: agg[row] += xd[col] + w_attr*attr ---------------
__global__ __launch_bounds__(256) void edge_scatter(
    const int* __restrict__ row, const int* __restrict__ col,
    const float* __restrict__ attr, const float* __restrict__ W,
    const float* __restrict__ xd, float* __restrict__ agg, int E)
{
    int gid = blockIdx.x * 256 + threadIdx.x;   // 16 threads per edge
    int e = gid >> 4;
    if (e >= E) return;
    int j4 = (gid & 15) << 2;
    int r = row[e], c = col[e];
    float a = attr[e];
    const float4 xv = *(const float4*)(xd + (size_t)c * H + j4);
    // attr-column of msg_W (stride 129, scalar loads, L1-broadcast)
    float w0 = W[(j4 + 0) * 129 + 128];
    float w1 = W[(j4 + 1) * 129 + 128];
    float w2 = W[(j4 + 2) * 129 + 128];
    float w3 = W[(j4 + 3) * 129 + 128];
    float* dst = agg + (size_t)r * H + j4;
    atomicAdd(dst + 0, fmaf(w0, a, xv.x));
    atomicAdd(dst + 1, fmaf(w1, a, xv.y));
    atomicAdd(dst + 2, fmaf(w2, a, xv.z));
    atomicAdd(dst + 3, fmaf(w3, a, xv.w));
}

// ---------------- fused GRU cell: x = GRU(agg, x) -------------------------------
#define GNPW 8   // nodes per wave
__global__ __launch_bounds__(256) void gru_kernel(
    const float* __restrict__ agg, float* __restrict__ x,
    const float* __restrict__ Wih, const float* __restrict__ bih,
    const float* __restrict__ Whh, const float* __restrict__ bhh, int N)
{
    // stage 32 k-columns of Wih^T / Whh^T per chunk; layout [kk][row], pad 193
    __shared__ float Wi[32 * 193];
    __shared__ float Wh[32 * 193];
    const int tid = threadIdx.x, lane = tid & 63, wv = tid >> 6;
    const int base = (blockIdx.x * 4 + wv) * GNPW;

    float a[GNPW], h[GNPW];
#pragma unroll
    for (int i = 0; i < GNPW; i++) {
        int n = base + i;
        a[i] = (n < N) ? agg[(size_t)n * H + lane] : 0.f;
        h[i] = (n < N) ? x[(size_t)n * H + lane] : 0.f;
    }
    float ir[GNPW], iz[GNPW], in_[GNPW], hr[GNPW], hz[GNPW], hn[GNPW];
    const float bir = bih[lane], biz = bih[64 + lane], bin = bih[128 + lane];
    const float bhr = bhh[lane], bhz = bhh[64 + lane], bhn = bhh[128 + lane];
#pragma unroll
    for (int i = 0; i < GNPW; i++) {
        ir[i] = bir; iz[i] = biz; in_[i] = bin;
        hr[i] = bhr; hz[i] = bhz; hn[i] = bhn;
    }

    for (int ch = 0; ch < 2; ch++) {
        if (ch) __syncthreads();
        for (int l = tid; l < 192 * 32; l += 256) {
            int i = l & 31, r = l >> 5;
            Wi[i * 193 + r] = Wih[r * 64 + ch * 32 + i];
            Wh[i * 193 + r] = Whh[r * 64 + ch * 32 + i];
        }
        __syncthreads();
#pragma unroll 4
        for (int kk = 0; kk < 32; kk++) {
            int k = ch * 32 + kk;
            float wir = Wi[kk * 193 + lane];
            float wiz = Wi[kk * 193 + 64 + lane];
            float win = Wi[kk * 193 + 128 + lane];
            float whr = Wh[kk * 193 + lane];
            float whz = Wh[kk * 193 + 64 + lane];
            float whn = Wh[kk * 193 + 128 + lane];
#pragma unroll
            for (int i = 0; i < GNPW; i++) {
                float ak = lane_bcast(a[i], k);
                float hk = lane_bcast(h[i], k);
                ir[i] = fmaf(wir, ak, ir[i]);
                iz[i] = fmaf(wiz, ak, iz[i]);
                in_[i] = fmaf(win, ak, in_[i]);
                hr[i] = fmaf(whr, hk, hr[i]);
                hz[i] = fmaf(whz, hk, hz[i]);
                hn[i] = fmaf(whn, hk, hn[i]);
            }
        }
    }

#pragma unroll
    for (int i = 0; i < GNPW; i++) {
        int n = base + i;
        if (n < N) {
            float r  = 1.f / (1.f + __expf(-(ir[i] + hr[i])));
            float z  = 1.f / (1.f + __expf(-(iz[i] + hz[i])));
            float e2 = __expf(2.f * (in_[i] + r * hn[i]));
            float nn = 1.f - 2.f / (e2 + 1.f);           // tanh
            x[(size_t)n * H + lane] = (1.f - z) * nn + z * h[i];
        }
    }
}

extern "C" void kernel_launch(void* const* d_in, const int* in_sizes, int n_in,
                              void* d_out, int out_size, void* d_ws, size_t ws_size,
                              hipStream_t stream) {
    const float* x_in  = (const float*)d_in[0];
    const int*   ei    = (const int*)d_in[1];
    const float* attr  = (const float*)d_in[2];
    const float* msg_W = (const float*)d_in[3];
    const float* msg_b = (const float*)d_in[4];
    const float* Wih   = (const float*)d_in[5];
    const float* bih   = (const float*)d_in[6];
    const float* Whh   = (const float*)d_in[7];
    const float* bhh   = (const float*)d_in[8];

    const int N = in_sizes[0] / H;        // 100000
    const int E = in_sizes[2];            // 1250000
    const int T = in_sizes[4] / H;        // 2
    const int* row = ei;
    const int* col = ei + E;

    float* x   = (float*)d_out;                    // live node state
    float* xd  = (float*)d_ws;                     // [N,64]
    float* agg = xd + (size_t)N * H;               // [N,64]
    int*   deg = (int*)(agg + (size_t)N * H);      // [N]

    hipMemcpyAsync(x, x_in, (size_t)N * H * sizeof(float),
                   hipMemcpyDeviceToDevice, stream);
    hipMemsetAsync(deg, 0, (size_t)N * sizeof(int), stream);
    deg_count<<<(E + 255) / 256, 256, 0, stream>>>(row, deg, E);

    const int node_blocks = (N + 31) / 32;         // 32 nodes per 256-thread block
    const int edge_blocks = (E * 16 + 255) / 256;  // 16 threads per edge

    for (int t = 0; t < T; t++) {
        const float* Wt = msg_W + (size_t)t * H * (2 * H + 1);
        node_transform<<<node_blocks, 256, 0, stream>>>(
            x, Wt, msg_b + (size_t)t * H, deg, xd, agg, N);
        edge_scatter<<<edge_blocks, 256, 0, stream>>>(
            row, col, attr, Wt, xd, agg, E);
        gru_kernel<<<node_blocks, 256, 0, stream>>>(
            agg, x,
            Wih + (size_t)t * 3 * H * H, bih + (size_t)t * 3 * H,
            Whh + (size_t)t * 3 * H * H, bhh + (size_t)t * 3 * H, N);
    }
}

// Round 2
// 796.771 us; speedup vs baseline: 3.2721x; 3.2721x over previous
//
#include <hip/hip_runtime.h>
#include <hip/hip_bf16.h>

#define H 64

__device__ __forceinline__ float lane_bcast(float v, int k) {
    return __int_as_float(__builtin_amdgcn_readlane(__float_as_int(v), k));
}

// ---------------- histogram: deg[n], attr_sum[n] over edge rows ----------------
__global__ __launch_bounds__(256) void hist_kernel(
    const int* __restrict__ row, const float* __restrict__ attr,
    int* __restrict__ deg, float* __restrict__ attr_sum, int E)
{
    int e = blockIdx.x * 256 + threadIdx.x;
    if (e < E) {
        int r = row[e];
        atomicAdd(&deg[r], 1);
        atomicAdd(&attr_sum[r], attr[e]);
    }
}

// ---------------- 3-phase exclusive scan of deg -> offsets ---------------------
__global__ __launch_bounds__(256) void scan_block(
    const int* __restrict__ deg, int* __restrict__ offsets,
    int* __restrict__ block_sums, int N)
{
    __shared__ int s[256];
    int tid = threadIdx.x, gid = blockIdx.x * 256 + tid;
    int v = (gid < N) ? deg[gid] : 0;
    s[tid] = v; __syncthreads();
    for (int off = 1; off < 256; off <<= 1) {
        int t = (tid >= off) ? s[tid - off] : 0;
        __syncthreads();
        s[tid] += t;
        __syncthreads();
    }
    if (gid < N) offsets[gid] = s[tid] - v;   // exclusive
    if (tid == 255) block_sums[blockIdx.x] = s[255];
}

__global__ __launch_bounds__(512) void scan_sums(int* __restrict__ block_sums, int nb)
{
    __shared__ int s[512];
    int tid = threadIdx.x;
    int v = (tid < nb) ? block_sums[tid] : 0;
    s[tid] = v; __syncthreads();
    for (int off = 1; off < 512; off <<= 1) {
        int t = (tid >= off) ? s[tid - off] : 0;
        __syncthreads();
        s[tid] += t;
        __syncthreads();
    }
    if (tid < nb) block_sums[tid] = s[tid] - v;  // exclusive
}

__global__ __launch_bounds__(256) void scan_add(
    int* __restrict__ offsets, const int* __restrict__ block_sums,
    int* __restrict__ cursor, int N, int E)
{
    int gid = blockIdx.x * 256 + threadIdx.x;
    if (gid < N) {
        int o = offsets[gid] + block_sums[blockIdx.x];
        offsets[gid] = o;
        cursor[gid] = o;
    }
    if (gid == 0) offsets[N] = E;
}

// ---------------- scatter edges into CSR order ---------------------------------
__global__ __launch_bounds__(256) void build_csr(
    const int* __restrict__ row, const int* __restrict__ col,
    int* __restrict__ cursor, int* __restrict__ col_sorted, int E)
{
    int e = blockIdx.x * 256 + threadIdx.x;
    if (e < E) {
        int pos = atomicAdd(&cursor[row[e]], 1);
        col_sorted[pos] = col[e];
    }
}

// ---------------- per-node transform -------------------------------------------
// xd[n] = Wd*x_n ;  agg[n] = deg[n]*(Ws*x_n + b) + w_attr*attr_sum[n]
// msg_W layout: [64 rows][129 cols]; cols 0..63 dest, 64..127 src, 128 attr.
#define TNPW 8
__global__ __launch_bounds__(256) void node_transform(
    const float* __restrict__ x, const float* __restrict__ W,
    const float* __restrict__ b, const int* __restrict__ offsets,
    const float* __restrict__ attr_sum,
    float* __restrict__ xd, float* __restrict__ agg, int N)
{
    __shared__ float Wd[64 * 65];
    __shared__ float Ws[64 * 65];
    const int tid = threadIdx.x, lane = tid & 63, wv = tid >> 6;

    for (int l = tid; l < 64 * 64; l += 256) {
        int k = l & 63, j = l >> 6;
        Wd[k * 65 + j] = W[j * 129 + k];
        Ws[k * 65 + j] = W[j * 129 + 64 + k];
    }
    __syncthreads();

    const int base = (blockIdx.x * 4 + wv) * TNPW;
    float xv[TNPW], ad[TNPW], as_[TNPW];
    const float bj = b[lane];
    const float wa = W[lane * 129 + 128];
#pragma unroll
    for (int i = 0; i < TNPW; i++) {
        int n = base + i;
        xv[i] = (n < N) ? x[(size_t)n * H + lane] : 0.f;
        ad[i] = 0.f; as_[i] = 0.f;
    }
#pragma unroll 4
    for (int k = 0; k < 64; k++) {
        float wd = Wd[k * 65 + lane];
        float ws = Ws[k * 65 + lane];
#pragma unroll
        for (int i = 0; i < TNPW; i++) {
            float xk = lane_bcast(xv[i], k);
            ad[i]  = fmaf(wd, xk, ad[i]);
            as_[i] = fmaf(ws, xk, as_[i]);
        }
    }
#pragma unroll
    for (int i = 0; i < TNPW; i++) {
        int n = base + i;
        if (n < N) {
            float dg = (float)(offsets[n + 1] - offsets[n]);
            xd[(size_t)n * H + lane]  = ad[i];
            agg[(size_t)n * H + lane] = dg * (as_[i] + bj) + wa * attr_sum[n];
        }
    }
}

// ---------------- gather aggregation: agg[n] += sum_e xd[col_e] ----------------
__global__ __launch_bounds__(256) void aggregate(
    const int* __restrict__ offsets, const int* __restrict__ col_sorted,
    const float* __restrict__ xd, float* __restrict__ agg, int N)
{
    const int tid = threadIdx.x, lane = tid & 63, wv = tid >> 6;
    const int n = blockIdx.x * 4 + wv;
    if (n >= N) return;
    const int beg = offsets[n], end = offsets[n + 1];
    float acc = agg[(size_t)n * H + lane];
    for (int k = beg; k < end; k += 64) {
        int cnt = end - k; if (cnt > 64) cnt = 64;
        int cl = (k + lane < end) ? col_sorted[k + lane] : 0;
        for (int j = 0; j < cnt; j++) {
            int c = __builtin_amdgcn_readlane(cl, j);
            acc += xd[(size_t)c * H + lane];
        }
    }
    agg[(size_t)n * H + lane] = acc;
}

// ---------------- fused GRU cell: x = GRU(agg, x) -------------------------------
#define GNPW 8
__global__ __launch_bounds__(256) void gru_kernel(
    const float* __restrict__ agg, float* __restrict__ x,
    const float* __restrict__ Wih, const float* __restrict__ bih,
    const float* __restrict__ Whh, const float* __restrict__ bhh, int N)
{
    __shared__ float Wi[32 * 193];
    __shared__ float Wh[32 * 193];
    const int tid = threadIdx.x, lane = tid & 63, wv = tid >> 6;
    const int base = (blockIdx.x * 4 + wv) * GNPW;

    float a[GNPW], h[GNPW];
#pragma unroll
    for (int i = 0; i < GNPW; i++) {
        int n = base + i;
        a[i] = (n < N) ? agg[(size_t)n * H + lane] : 0.f;
        h[i] = (n < N) ? x[(size_t)n * H + lane] : 0.f;
    }
    float ir[GNPW], iz[GNPW], in_[GNPW], hr[GNPW], hz[GNPW], hn[GNPW];
    const float bir = bih[lane], biz = bih[64 + lane], bin = bih[128 + lane];
    const float bhr = bhh[lane], bhz = bhh[64 + lane], bhn = bhh[128 + lane];
#pragma unroll
    for (int i = 0; i < GNPW; i++) {
        ir[i] = bir; iz[i] = biz; in_[i] = bin;
        hr[i] = bhr; hz[i] = bhz; hn[i] = bhn;
    }

    for (int ch = 0; ch < 2; ch++) {
        if (ch) __syncthreads();
        for (int l = tid; l < 192 * 32; l += 256) {
            int i = l & 31, r = l >> 5;
            Wi[i * 193 + r] = Wih[r * 64 + ch * 32 + i];
            Wh[i * 193 + r] = Whh[r * 64 + ch * 32 + i];
        }
        __syncthreads();
#pragma unroll 4
        for (int kk = 0; kk < 32; kk++) {
            int k = ch * 32 + kk;
            float wir = Wi[kk * 193 + lane];
            float wiz = Wi[kk * 193 + 64 + lane];
            float win = Wi[kk * 193 + 128 + lane];
            float whr = Wh[kk * 193 + lane];
            float whz = Wh[kk * 193 + 64 + lane];
            float whn = Wh[kk * 193 + 128 + lane];
#pragma unroll
            for (int i = 0; i < GNPW; i++) {
                float ak = lane_bcast(a[i], k);
                float hk = lane_bcast(h[i], k);
                ir[i] = fmaf(wir, ak, ir[i]);
                iz[i] = fmaf(wiz, ak, iz[i]);
                in_[i] = fmaf(win, ak, in_[i]);
                hr[i] = fmaf(whr, hk, hr[i]);
                hz[i] = fmaf(whz, hk, hz[i]);
                hn[i] = fmaf(whn, hk, hn[i]);
            }
        }
    }

#pragma unroll
    for (int i = 0; i < GNPW; i++) {
        int n = base + i;
        if (n < N) {
            float r  = 1.f / (1.f + __expf(-(ir[i] + hr[i])));
            float z  = 1.f / (1.f + __expf(-(iz[i] + hz[i])));
            float e2 = __expf(2.f * (in_[i] + r * hn[i]));
            float nn = 1.f - 2.f / (e2 + 1.f);           // tanh
            x[(size_t)n * H + lane] = (1.f - z) * nn + z * h[i];
        }
    }
}

extern "C" void kernel_launch(void* const* d_in, const int* in_sizes, int n_in,
                              void* d_out, int out_size, void* d_ws, size_t ws_size,
                              hipStream_t stream) {
    const float* x_in  = (const float*)d_in[0];
    const int*   ei    = (const int*)d_in[1];
    const float* attr  = (const float*)d_in[2];
    const float* msg_W = (const float*)d_in[3];
    const float* msg_b = (const float*)d_in[4];
    const float* Wih   = (const float*)d_in[5];
    const float* bih   = (const float*)d_in[6];
    const float* Whh   = (const float*)d_in[7];
    const float* bhh   = (const float*)d_in[8];

    const int N = in_sizes[0] / H;        // 100000
    const int E = in_sizes[2];            // 1250000
    const int T = in_sizes[4] / H;        // 2
    const int* row = ei;
    const int* col = ei + E;

    // ---- workspace layout ----
    float* x        = (float*)d_out;                       // live node state [N,H]
    float* xd       = (float*)d_ws;                        // [N,H]
    float* agg      = xd + (size_t)N * H;                  // [N,H]
    float* attr_sum = agg + (size_t)N * H;                 // [N]
    int*   deg      = (int*)(attr_sum + N);                // [N]
    int*   offsets  = deg + N;                             // [N+1]
    int*   cursor   = offsets + (N + 1);                   // [N]
    int*   bsums    = cursor + N;                          // [512]
    int*   col_sorted = bsums + 512;                       // [E]

    const int nb = (N + 255) / 256;                        // 391 scan blocks
    const int eb = (E + 255) / 256;

    hipMemcpyAsync(x, x_in, (size_t)N * H * sizeof(float),
                   hipMemcpyDeviceToDevice, stream);
    hipMemsetAsync(deg, 0, (size_t)N * sizeof(int), stream);
    hipMemsetAsync(attr_sum, 0, (size_t)N * sizeof(float), stream);

    hist_kernel<<<eb, 256, 0, stream>>>(row, attr, deg, attr_sum, E);
    scan_block<<<nb, 256, 0, stream>>>(deg, offsets, bsums, N);
    scan_sums<<<1, 512, 0, stream>>>(bsums, nb);
    scan_add<<<nb, 256, 0, stream>>>(offsets, bsums, cursor, N, E);
    build_csr<<<eb, 256, 0, stream>>>(row, col, cursor, col_sorted, E);

    const int node_blocks = (N + 31) / 32;   // 32 nodes / 256-thread block
    const int agg_blocks  = (N + 3) / 4;     // 4 nodes (waves) / block

    for (int t = 0; t < T; t++) {
        const float* Wt = msg_W + (size_t)t * H * (2 * H + 1);
        node_transform<<<node_blocks, 256, 0, stream>>>(
            x, Wt, msg_b + (size_t)t * H, offsets, attr_sum, xd, agg, N);
        aggregate<<<agg_blocks, 256, 0, stream>>>(
            offsets, col_sorted, xd, agg, N);
        gru_kernel<<<node_blocks, 256, 0, stream>>>(
            agg, x,
            Wih + (size_t)t * 3 * H * H, bih + (size_t)t * 3 * H,
            Whh + (size_t)t * 3 * H * H, bhh + (size_t)t * 3 * H, N);
    }
}

// Round 3
// 725.412 us; speedup vs baseline: 3.5940x; 1.0984x over previous
//
#include <hip/hip_runtime.h>
#include <hip/hip_bf16.h>

#define H 64

typedef __attribute__((ext_vector_type(8))) short short8;
typedef __attribute__((ext_vector_type(4))) float float4v;

__device__ __forceinline__ short f2bf_bits(float f) {
    union { __hip_bfloat16 b; short s; } u;
    u.b = __float2bfloat16(f);
    return u.s;
}
__device__ __forceinline__ float bf2f(short s) {
    union { __hip_bfloat16 b; short s2; } u;
    u.s2 = s;
    return __bfloat162float(u.b);
}
// split 8 consecutive floats into bf16 hi + lo fragments (RNE both)
__device__ __forceinline__ void split8(const float* __restrict__ p,
                                       short8& hi, short8& lo) {
    float4v f0 = *(const float4v*)p;
    float4v f1 = *(const float4v*)(p + 4);
#pragma unroll
    for (int j = 0; j < 8; j++) {
        float f = (j < 4) ? f0[j] : f1[j - 4];
        short h = f2bf_bits(f);
        float fh = bf2f(h);
        hi[j] = h;
        lo[j] = f2bf_bits(f - fh);
    }
}
__device__ __forceinline__ void zero8(short8& hi, short8& lo) {
#pragma unroll
    for (int j = 0; j < 8; j++) { hi[j] = 0; lo[j] = 0; }
}

#define MFMA(a, b, c) __builtin_amdgcn_mfma_f32_16x16x32_bf16(a, b, c, 0, 0, 0)

// ---------------- histogram: deg[n], attr_sum[n] over edge rows ----------------
__global__ __launch_bounds__(256) void hist_kernel(
    const int* __restrict__ row, const float* __restrict__ attr,
    int* __restrict__ deg, float* __restrict__ attr_sum, int E)
{
    int e = blockIdx.x * 256 + threadIdx.x;
    if (e < E) {
        int r = row[e];
        atomicAdd(&deg[r], 1);
        atomicAdd(&attr_sum[r], attr[e]);
    }
}

// ---------------- 3-phase exclusive scan of deg -> offsets ---------------------
__global__ __launch_bounds__(256) void scan_block(
    const int* __restrict__ deg, int* __restrict__ offsets,
    int* __restrict__ block_sums, int N)
{
    __shared__ int s[256];
    int tid = threadIdx.x, gid = blockIdx.x * 256 + tid;
    int v = (gid < N) ? deg[gid] : 0;
    s[tid] = v; __syncthreads();
    for (int off = 1; off < 256; off <<= 1) {
        int t = (tid >= off) ? s[tid - off] : 0;
        __syncthreads();
        s[tid] += t;
        __syncthreads();
    }
    if (gid < N) offsets[gid] = s[tid] - v;   // exclusive
    if (tid == 255) block_sums[blockIdx.x] = s[255];
}

__global__ __launch_bounds__(512) void scan_sums(int* __restrict__ block_sums, int nb)
{
    __shared__ int s[512];
    int tid = threadIdx.x;
    int v = (tid < nb) ? block_sums[tid] : 0;
    s[tid] = v; __syncthreads();
    for (int off = 1; off < 512; off <<= 1) {
        int t = (tid >= off) ? s[tid - off] : 0;
        __syncthreads();
        s[tid] += t;
        __syncthreads();
    }
    if (tid < nb) block_sums[tid] = s[tid] - v;  // exclusive
}

__global__ __launch_bounds__(256) void scan_add(
    int* __restrict__ offsets, const int* __restrict__ block_sums,
    int* __restrict__ cursor, int N, int E)
{
    int gid = blockIdx.x * 256 + threadIdx.x;
    if (gid < N) {
        int o = offsets[gid] + block_sums[blockIdx.x];
        offsets[gid] = o;
        cursor[gid] = o;
    }
    if (gid == 0) offsets[N] = E;
}

// ---------------- scatter edges into CSR order ---------------------------------
__global__ __launch_bounds__(256) void build_csr(
    const int* __restrict__ row, const int* __restrict__ col,
    int* __restrict__ cursor, int* __restrict__ col_sorted, int E)
{
    int e = blockIdx.x * 256 + threadIdx.x;
    if (e < E) {
        int pos = atomicAdd(&cursor[row[e]], 1);
        col_sorted[pos] = col[e];
    }
}

// ---------------- node transform (MFMA, split-bf16) ----------------------------
// out[n][0..63]  = xd[n]  = Wd * x_n          (tiles 0..3)
// out[n][64..127]= xs[n]  = Ws * x_n ; agg[n] = deg*(xs+b) + wa*attr_sum (tiles 4..7)
// msg_W: [64 rows][129 cols], cols 0..63 dest(Wd), 64..127 src(Ws), 128 attr.
__global__ __launch_bounds__(256) void node_transform_mfma(
    const float* __restrict__ x, const float* __restrict__ W,
    const float* __restrict__ b, const int* __restrict__ deg,
    const float* __restrict__ attr_sum,
    float* __restrict__ xd, float* __restrict__ agg, int N)
{
    const int tid = threadIdx.x, lane = tid & 63, wv = tid >> 6;
    const int base = (blockIdx.x * 4 + wv) * 16;
    const int mrow = base + (lane & 15);
    const int kq = (lane >> 4) * 8;

    short8 ah[2], al[2];
#pragma unroll
    for (int ks = 0; ks < 2; ks++) {
        if (mrow < N) split8(x + (size_t)mrow * H + ks * 32 + kq, ah[ks], al[ks]);
        else          zero8(ah[ks], al[ks]);
    }

    float4v acc[8];
#pragma unroll
    for (int t = 0; t < 8; t++) acc[t] = (float4v){0.f, 0.f, 0.f, 0.f};

#pragma unroll
    for (int t = 0; t < 8; t++) {
        const int wrow = ((t & 3) * 16) + (lane & 15);
        const int coff = (t < 4) ? 0 : 64;
#pragma unroll
        for (int ks = 0; ks < 2; ks++) {
            short8 bh, bl;
            split8(W + (size_t)wrow * 129 + coff + ks * 32 + kq, bh, bl);
            acc[t] = MFMA(ah[ks], bh, acc[t]);
            acc[t] = MFMA(al[ks], bh, acc[t]);
            acc[t] = MFMA(ah[ks], bl, acc[t]);
        }
    }

    const int colb = lane & 15;
    const int rquad = (lane >> 4) * 4;
#pragma unroll
    for (int r = 0; r < 4; r++) {
        const int m = base + rquad + r;
        if (m >= N) continue;
        const float dg = (float)deg[m];
        const float asum = attr_sum[m];
#pragma unroll
        for (int t = 0; t < 4; t++) {
            const int col = t * 16 + colb;
            xd[(size_t)m * H + col] = acc[t][r];
            agg[(size_t)m * H + col] =
                dg * (acc[4 + t][r] + b[col]) + W[(size_t)col * 129 + 128] * asum;
        }
    }
}

// ---------------- gather aggregation: agg[n] += sum_e xd[col_e] ----------------
__global__ __launch_bounds__(256) void aggregate(
    const int* __restrict__ offsets, const int* __restrict__ col_sorted,
    const float* __restrict__ xd, float* __restrict__ agg, int N)
{
    const int tid = threadIdx.x, lane = tid & 63, wv = tid >> 6;
    const int n = blockIdx.x * 4 + wv;
    if (n >= N) return;
    const int beg = offsets[n], end = offsets[n + 1];
    float acc = agg[(size_t)n * H + lane];
    for (int k = beg; k < end; k += 64) {
        int cnt = end - k; if (cnt > 64) cnt = 64;
        int cl = (k + lane < end) ? col_sorted[k + lane] : 0;
        for (int j = 0; j < cnt; j++) {
            int c = __builtin_amdgcn_readlane(cl, j);
            acc += xd[(size_t)c * H + lane];
        }
    }
    agg[(size_t)n * H + lane] = acc;
}

// ---------------- GRU cell (MFMA, split-bf16) -----------------------------------
// gi = agg @ Wih^T (tiles 0..11), gh = h @ Whh^T (tiles 12..23); gates per-lane.
__global__ __launch_bounds__(256) void gru_mfma(
    const float* __restrict__ agg, float* __restrict__ x,
    const float* __restrict__ Wih, const float* __restrict__ bih,
    const float* __restrict__ Whh, const float* __restrict__ bhh, int N)
{
    const int tid = threadIdx.x, lane = tid & 63, wv = tid >> 6;
    const int base = (blockIdx.x * 4 + wv) * 16;
    const int mrow = base + (lane & 15);
    const int kq = (lane >> 4) * 8;

    short8 gah[2], gal[2], hh[2], hl[2];
#pragma unroll
    for (int ks = 0; ks < 2; ks++) {
        if (mrow < N) {
            split8(agg + (size_t)mrow * H + ks * 32 + kq, gah[ks], gal[ks]);
            split8(x   + (size_t)mrow * H + ks * 32 + kq, hh[ks],  hl[ks]);
        } else { zero8(gah[ks], gal[ks]); zero8(hh[ks], hl[ks]); }
    }

    float4v acc[24];
#pragma unroll
    for (int t = 0; t < 24; t++) acc[t] = (float4v){0.f, 0.f, 0.f, 0.f};

#pragma unroll
    for (int t = 0; t < 24; t++) {
        const float* Wp = (t < 12)
            ? (Wih + ((size_t)(t * 16 + (lane & 15))) * H)
            : (Whh + ((size_t)((t - 12) * 16 + (lane & 15))) * H);
#pragma unroll
        for (int ks = 0; ks < 2; ks++) {
            short8 bh, bl;
            split8(Wp + ks * 32 + kq, bh, bl);
            if (t < 12) {
                acc[t] = MFMA(gah[ks], bh, acc[t]);
                acc[t] = MFMA(gal[ks], bh, acc[t]);
                acc[t] = MFMA(gah[ks], bl, acc[t]);
            } else {
                acc[t] = MFMA(hh[ks], bh, acc[t]);
                acc[t] = MFMA(hl[ks], bh, acc[t]);
                acc[t] = MFMA(hh[ks], bl, acc[t]);
            }
        }
    }

    const int colb = lane & 15;
    const int rquad = (lane >> 4) * 4;
#pragma unroll
    for (int j4 = 0; j4 < 4; j4++) {
        const int j = j4 * 16 + colb;
        const float b_ir = bih[j],       b_hr = bhh[j];
        const float b_iz = bih[64 + j],  b_hz = bhh[64 + j];
        const float b_in = bih[128 + j], b_hn = bhh[128 + j];
#pragma unroll
        for (int r = 0; r < 4; r++) {
            const int m = base + rquad + r;
            if (m >= N) continue;
            float ir = acc[j4][r]      + b_ir;
            float hr = acc[12 + j4][r] + b_hr;
            float iz = acc[4 + j4][r]  + b_iz;
            float hz = acc[16 + j4][r] + b_hz;
            float in_ = acc[8 + j4][r]  + b_in;
            float hn  = acc[20 + j4][r] + b_hn;
            float rr = 1.f / (1.f + __expf(-(ir + hr)));
            float zz = 1.f / (1.f + __expf(-(iz + hz)));
            float e2 = __expf(2.f * (in_ + rr * hn));
            float nn = 1.f - 2.f / (e2 + 1.f);          // tanh
            float hold = x[(size_t)m * H + j];
            x[(size_t)m * H + j] = (1.f - zz) * nn + zz * hold;
        }
    }
}

extern "C" void kernel_launch(void* const* d_in, const int* in_sizes, int n_in,
                              void* d_out, int out_size, void* d_ws, size_t ws_size,
                              hipStream_t stream) {
    const float* x_in  = (const float*)d_in[0];
    const int*   ei    = (const int*)d_in[1];
    const float* attr  = (const float*)d_in[2];
    const float* msg_W = (const float*)d_in[3];
    const float* msg_b = (const float*)d_in[4];
    const float* Wih   = (const float*)d_in[5];
    const float* bih   = (const float*)d_in[6];
    const float* Whh   = (const float*)d_in[7];
    const float* bhh   = (const float*)d_in[8];

    const int N = in_sizes[0] / H;        // 100000
    const int E = in_sizes[2];            // 1250000
    const int T = in_sizes[4] / H;        // 2
    const int* row = ei;
    const int* col = ei + E;

    // ---- workspace layout ----
    float* x        = (float*)d_out;                       // live node state [N,H]
    float* xd       = (float*)d_ws;                        // [N,H]
    float* agg      = xd + (size_t)N * H;                  // [N,H]
    float* attr_sum = agg + (size_t)N * H;                 // [N]
    int*   deg      = (int*)(attr_sum + N);                // [N]
    int*   offsets  = deg + N;                             // [N+1]
    int*   cursor   = offsets + (N + 1);                   // [N]
    int*   bsums    = cursor + N;                          // [512]
    int*   col_sorted = bsums + 512;                       // [E]

    const int nb = (N + 255) / 256;
    const int eb = (E + 255) / 256;

    hipMemcpyAsync(x, x_in, (size_t)N * H * sizeof(float),
                   hipMemcpyDeviceToDevice, stream);
    hipMemsetAsync(deg, 0, (size_t)N * sizeof(int), stream);
    hipMemsetAsync(attr_sum, 0, (size_t)N * sizeof(float), stream);

    hist_kernel<<<eb, 256, 0, stream>>>(row, attr, deg, attr_sum, E);
    scan_block<<<nb, 256, 0, stream>>>(deg, offsets, bsums, N);
    scan_sums<<<1, 512, 0, stream>>>(bsums, nb);
    scan_add<<<nb, 256, 0, stream>>>(offsets, bsums, cursor, N, E);
    build_csr<<<eb, 256, 0, stream>>>(row, col, cursor, col_sorted, E);

    const int nb64 = (N + 63) / 64;          // 64 nodes / 256-thread block
    const int agg_blocks = (N + 3) / 4;      // 4 nodes (waves) / block

    for (int t = 0; t < T; t++) {
        const float* Wt = msg_W + (size_t)t * H * (2 * H + 1);
        node_transform_mfma<<<nb64, 256, 0, stream>>>(
            x, Wt, msg_b + (size_t)t * H, deg, attr_sum, xd, agg, N);
        aggregate<<<agg_blocks, 256, 0, stream>>>(
            offsets, col_sorted, xd, agg, N);
        gru_mfma<<<nb64, 256, 0, stream>>>(
            agg, x,
            Wih + (size_t)t * 3 * H * H, bih + (size_t)t * 3 * H,
            Whh + (size_t)t * 3 * H * H, bhh + (size_t)t * 3 * H, N);
    }
}

// Round 4
// 624.430 us; speedup vs baseline: 4.1752x; 1.1617x over previous
//
#include <hip/hip_runtime.h>
#include <hip/hip_bf16.h>

#define H 64

typedef __attribute__((ext_vector_type(8))) short short8;
typedef __attribute__((ext_vector_type(4))) float float4v;

__device__ __forceinline__ float lane_bcast(float v, int k) {
    return __int_as_float(__builtin_amdgcn_readlane(__float_as_int(v), k));
}
__device__ __forceinline__ short f2bf_bits(float f) {
    union { __hip_bfloat16 b; short s; } u;
    u.b = __float2bfloat16(f);
    return u.s;
}
__device__ __forceinline__ float bf2f(unsigned short s) {
    union { unsigned int u; float f; } v;
    v.u = ((unsigned int)s) << 16;
    return v.f;
}
// split 8 consecutive floats into bf16 hi + lo fragments
__device__ __forceinline__ void split8(const float* __restrict__ p,
                                       short8& hi, short8& lo) {
    float4v f0 = *(const float4v*)p;
    float4v f1 = *(const float4v*)(p + 4);
#pragma unroll
    for (int j = 0; j < 8; j++) {
        float f = (j < 4) ? f0[j] : f1[j - 4];
        short h = f2bf_bits(f);
        float fh = bf2f((unsigned short)h);
        hi[j] = h;
        lo[j] = f2bf_bits(f - fh);
    }
}
__device__ __forceinline__ void zero8(short8& hi, short8& lo) {
#pragma unroll
    for (int j = 0; j < 8; j++) { hi[j] = 0; lo[j] = 0; }
}

#define MFMA(a, b, c) __builtin_amdgcn_mfma_f32_16x16x32_bf16(a, b, c, 0, 0, 0)

// ---------------- count: deg[n] += 1, record local position --------------------
__global__ __launch_bounds__(256) void count_kernel(
    const int* __restrict__ row, int* __restrict__ deg,
    int* __restrict__ lpos, int E)
{
    int e = blockIdx.x * 256 + threadIdx.x;
    if (e < E) lpos[e] = atomicAdd(&deg[row[e]], 1);
}

// ---------------- 3-phase exclusive scan of deg -> offsets ---------------------
__global__ __launch_bounds__(256) void scan_block(
    const int* __restrict__ deg, int* __restrict__ offsets,
    int* __restrict__ block_sums, int N)
{
    __shared__ int s[256];
    int tid = threadIdx.x, gid = blockIdx.x * 256 + tid;
    int v = (gid < N) ? deg[gid] : 0;
    s[tid] = v; __syncthreads();
    for (int off = 1; off < 256; off <<= 1) {
        int t = (tid >= off) ? s[tid - off] : 0;
        __syncthreads();
        s[tid] += t;
        __syncthreads();
    }
    if (gid < N) offsets[gid] = s[tid] - v;   // exclusive
    if (tid == 255) block_sums[blockIdx.x] = s[255];
}

__global__ __launch_bounds__(512) void scan_sums(int* __restrict__ block_sums, int nb)
{
    __shared__ int s[512];
    int tid = threadIdx.x;
    int v = (tid < nb) ? block_sums[tid] : 0;
    s[tid] = v; __syncthreads();
    for (int off = 1; off < 512; off <<= 1) {
        int t = (tid >= off) ? s[tid - off] : 0;
        __syncthreads();
        s[tid] += t;
        __syncthreads();
    }
    if (tid < nb) block_sums[tid] = s[tid] - v;  // exclusive
}

__global__ __launch_bounds__(256) void scan_add(
    int* __restrict__ offsets, const int* __restrict__ block_sums, int N, int E)
{
    int gid = blockIdx.x * 256 + threadIdx.x;
    if (gid < N) offsets[gid] += block_sums[blockIdx.x];
    if (gid == 0) offsets[N] = E;
}

// ---------------- atomic-free CSR scatter --------------------------------------
__global__ __launch_bounds__(256) void scatter_kernel(
    const int* __restrict__ row, const int* __restrict__ col,
    const float* __restrict__ attr, const int* __restrict__ offsets,
    const int* __restrict__ lpos,
    int* __restrict__ col_sorted, float* __restrict__ attr_sorted, int E)
{
    int e = blockIdx.x * 256 + threadIdx.x;
    if (e < E) {
        int p = offsets[row[e]] + lpos[e];
        col_sorted[p] = col[e];
        attr_sorted[p] = attr[e];
    }
}

// ---------------- node transform (MFMA, split-bf16) ----------------------------
// xd[n] (bf16) = Wd * x_n (tiles 0..3); agg[n] = deg*(Ws*x_n + b) (tiles 4..7)
// msg_W: [64 rows][129 cols], cols 0..63 dest(Wd), 64..127 src(Ws), 128 attr.
__global__ __launch_bounds__(256) void node_transform_mfma(
    const float* __restrict__ x, const float* __restrict__ W,
    const float* __restrict__ b, const int* __restrict__ deg,
    unsigned short* __restrict__ xd, float* __restrict__ agg, int N)
{
    const int tid = threadIdx.x, lane = tid & 63, wv = tid >> 6;
    const int base = (blockIdx.x * 4 + wv) * 16;
    const int mrow = base + (lane & 15);
    const int kq = (lane >> 4) * 8;

    short8 ah[2], al[2];
#pragma unroll
    for (int ks = 0; ks < 2; ks++) {
        if (mrow < N) split8(x + (size_t)mrow * H + ks * 32 + kq, ah[ks], al[ks]);
        else          zero8(ah[ks], al[ks]);
    }

    float4v acc[8];
#pragma unroll
    for (int t = 0; t < 8; t++) acc[t] = (float4v){0.f, 0.f, 0.f, 0.f};

#pragma unroll
    for (int t = 0; t < 8; t++) {
        const int wrow = ((t & 3) * 16) + (lane & 15);
        const int coff = (t < 4) ? 0 : 64;
#pragma unroll
        for (int ks = 0; ks < 2; ks++) {
            short8 bh, bl;
            split8(W + (size_t)wrow * 129 + coff + ks * 32 + kq, bh, bl);
            acc[t] = MFMA(ah[ks], bh, acc[t]);
            acc[t] = MFMA(al[ks], bh, acc[t]);
            acc[t] = MFMA(ah[ks], bl, acc[t]);
        }
    }

    const int colb = lane & 15;
    const int rquad = (lane >> 4) * 4;
#pragma unroll
    for (int r = 0; r < 4; r++) {
        const int m = base + rquad + r;
        if (m >= N) continue;
        const float dg = (float)deg[m];
#pragma unroll
        for (int t = 0; t < 4; t++) {
            const int col = t * 16 + colb;
            xd[(size_t)m * H + col] = (unsigned short)f2bf_bits(acc[t][r]);
            agg[(size_t)m * H + col] = dg * (acc[4 + t][r] + b[col]);
        }
    }
}

// ---------------- gather aggregation -------------------------------------------
// agg[n][j] += sum_e ( xd_bf16[col_e][j] + wa[j]*attr_e )
__global__ __launch_bounds__(256) void aggregate(
    const int* __restrict__ offsets, const int* __restrict__ col_sorted,
    const float* __restrict__ attr_sorted, const unsigned short* __restrict__ xd,
    const float* __restrict__ W, float* __restrict__ agg, int N)
{
    const int tid = threadIdx.x, lane = tid & 63, wv = tid >> 6;
    const int n = blockIdx.x * 4 + wv;
    if (n >= N) return;
    const float wa = W[(size_t)lane * 129 + 128];
    const int beg = offsets[n], end = offsets[n + 1];
    float acc = agg[(size_t)n * H + lane];
    for (int k = beg; k < end; k += 64) {
        int cnt = end - k; if (cnt > 64) cnt = 64;
        int cl = 0; float al = 0.f;
        if (k + lane < end) {
            cl = col_sorted[k + lane];
            al = attr_sorted[k + lane];
        }
        for (int j = 0; j < cnt; j++) {
            int c = __builtin_amdgcn_readlane(cl, j);
            float a = lane_bcast(al, j);
            float v = bf2f(xd[(size_t)c * H + lane]);
            acc += fmaf(wa, a, v);
        }
    }
    agg[(size_t)n * H + lane] = acc;
}

// ---------------- GRU cell (MFMA, split-bf16) -----------------------------------
__global__ __launch_bounds__(256) void gru_mfma(
    const float* __restrict__ agg, float* __restrict__ x,
    const float* __restrict__ Wih, const float* __restrict__ bih,
    const float* __restrict__ Whh, const float* __restrict__ bhh, int N)
{
    const int tid = threadIdx.x, lane = tid & 63, wv = tid >> 6;
    const int base = (blockIdx.x * 4 + wv) * 16;
    const int mrow = base + (lane & 15);
    const int kq = (lane >> 4) * 8;

    short8 gah[2], gal[2], hh[2], hl[2];
#pragma unroll
    for (int ks = 0; ks < 2; ks++) {
        if (mrow < N) {
            split8(agg + (size_t)mrow * H + ks * 32 + kq, gah[ks], gal[ks]);
            split8(x   + (size_t)mrow * H + ks * 32 + kq, hh[ks],  hl[ks]);
        } else { zero8(gah[ks], gal[ks]); zero8(hh[ks], hl[ks]); }
    }

    float4v acc[24];
#pragma unroll
    for (int t = 0; t < 24; t++) acc[t] = (float4v){0.f, 0.f, 0.f, 0.f};

#pragma unroll
    for (int t = 0; t < 24; t++) {
        const float* Wp = (t < 12)
            ? (Wih + ((size_t)(t * 16 + (lane & 15))) * H)
            : (Whh + ((size_t)((t - 12) * 16 + (lane & 15))) * H);
#pragma unroll
        for (int ks = 0; ks < 2; ks++) {
            short8 bh, bl;
            split8(Wp + ks * 32 + kq, bh, bl);
            if (t < 12) {
                acc[t] = MFMA(gah[ks], bh, acc[t]);
                acc[t] = MFMA(gal[ks], bh, acc[t]);
                acc[t] = MFMA(gah[ks], bl, acc[t]);
            } else {
                acc[t] = MFMA(hh[ks], bh, acc[t]);
                acc[t] = MFMA(hl[ks], bh, acc[t]);
                acc[t] = MFMA(hh[ks], bl, acc[t]);
            }
        }
    }

    const int colb = lane & 15;
    const int rquad = (lane >> 4) * 4;
#pragma unroll
    for (int j4 = 0; j4 < 4; j4++) {
        const int j = j4 * 16 + colb;
        const float b_ir = bih[j],       b_hr = bhh[j];
        const float b_iz = bih[64 + j],  b_hz = bhh[64 + j];
        const float b_in = bih[128 + j], b_hn = bhh[128 + j];
#pragma unroll
        for (int r = 0; r < 4; r++) {
            const int m = base + rquad + r;
            if (m >= N) continue;
            float ir = acc[j4][r]      + b_ir;
            float hr = acc[12 + j4][r] + b_hr;
            float iz = acc[4 + j4][r]  + b_iz;
            float hz = acc[16 + j4][r] + b_hz;
            float in_ = acc[8 + j4][r]  + b_in;
            float hn  = acc[20 + j4][r] + b_hn;
            float rr = 1.f / (1.f + __expf(-(ir + hr)));
            float zz = 1.f / (1.f + __expf(-(iz + hz)));
            float e2 = __expf(2.f * (in_ + rr * hn));
            float nn = 1.f - 2.f / (e2 + 1.f);          // tanh
            float hold = x[(size_t)m * H + j];
            x[(size_t)m * H + j] = (1.f - zz) * nn + zz * hold;
        }
    }
}

extern "C" void kernel_launch(void* const* d_in, const int* in_sizes, int n_in,
                              void* d_out, int out_size, void* d_ws, size_t ws_size,
                              hipStream_t stream) {
    const float* x_in  = (const float*)d_in[0];
    const int*   ei    = (const int*)d_in[1];
    const float* attr  = (const float*)d_in[2];
    const float* msg_W = (const float*)d_in[3];
    const float* msg_b = (const float*)d_in[4];
    const float* Wih   = (const float*)d_in[5];
    const float* bih   = (const float*)d_in[6];
    const float* Whh   = (const float*)d_in[7];
    const float* bhh   = (const float*)d_in[8];

    const int N = in_sizes[0] / H;        // 100000
    const int E = in_sizes[2];            // 1250000
    const int T = in_sizes[4] / H;        // 2
    const int* row = ei;
    const int* col = ei + E;

    // ---- workspace layout ----
    float* x          = (float*)d_out;                    // live node state [N,H]
    float* agg        = (float*)d_ws;                     // [N,H] f32
    unsigned short* xd = (unsigned short*)(agg + (size_t)N * H);  // [N,H] bf16
    int*   deg        = (int*)(xd + (size_t)N * H);       // [N]
    int*   offsets    = deg + N;                          // [N+1]
    int*   bsums      = offsets + (N + 1);                // [512]
    int*   lpos       = bsums + 512;                      // [E]
    int*   col_sorted = lpos + E;                         // [E]
    float* attr_sorted = (float*)(col_sorted + E);        // [E]

    const int nb = (N + 255) / 256;
    const int eb = (E + 255) / 256;

    hipMemcpyAsync(x, x_in, (size_t)N * H * sizeof(float),
                   hipMemcpyDeviceToDevice, stream);
    hipMemsetAsync(deg, 0, (size_t)N * sizeof(int), stream);

    count_kernel<<<eb, 256, 0, stream>>>(row, deg, lpos, E);
    scan_block<<<nb, 256, 0, stream>>>(deg, offsets, bsums, N);
    scan_sums<<<1, 512, 0, stream>>>(bsums, nb);
    scan_add<<<nb, 256, 0, stream>>>(offsets, bsums, N, E);
    scatter_kernel<<<eb, 256, 0, stream>>>(row, col, attr, offsets, lpos,
                                           col_sorted, attr_sorted, E);

    const int nb64 = (N + 63) / 64;          // 64 nodes / 256-thread block
    const int agg_blocks = (N + 3) / 4;      // 4 nodes (waves) / block

    for (int t = 0; t < T; t++) {
        const float* Wt = msg_W + (size_t)t * H * (2 * H + 1);
        node_transform_mfma<<<nb64, 256, 0, stream>>>(
            x, Wt, msg_b + (size_t)t * H, deg, xd, agg, N);
        aggregate<<<agg_blocks, 256, 0, stream>>>(
            offsets, col_sorted, attr_sorted, xd, Wt, agg, N);
        gru_mfma<<<nb64, 256, 0, stream>>>(
            agg, x,
            Wih + (size_t)t * 3 * H * H, bih + (size_t)t * 3 * H,
            Whh + (size_t)t * 3 * H * H, bhh + (size_t)t * 3 * H, N);
    }
}

// Round 5
// 464.552 us; speedup vs baseline: 5.6122x; 1.3442x over previous
//
#include <hip/hip_runtime.h>
#include <hip/hip_bf16.h>

#define H 64

typedef __attribute__((ext_vector_type(8))) short short8;
typedef __attribute__((ext_vector_type(4))) float float4v;

__device__ __forceinline__ float lane_bcast(float v, int k) {
    return __int_as_float(__builtin_amdgcn_readlane(__float_as_int(v), k));
}
__device__ __forceinline__ short f2bf_bits(float f) {
    union { __hip_bfloat16 b; short s; } u;
    u.b = __float2bfloat16(f);
    return u.s;
}
__device__ __forceinline__ float bf2f(unsigned short s) {
    union { unsigned int u; float f; } v;
    v.u = ((unsigned int)s) << 16;
    return v.f;
}
// split 8 consecutive floats into bf16 hi + lo fragments
__device__ __forceinline__ void split8(const float* __restrict__ p,
                                       short8& hi, short8& lo) {
    float4v f0 = *(const float4v*)p;
    float4v f1 = *(const float4v*)(p + 4);
#pragma unroll
    for (int j = 0; j < 8; j++) {
        float f = (j < 4) ? f0[j] : f1[j - 4];
        short h = f2bf_bits(f);
        float fh = bf2f((unsigned short)h);
        hi[j] = h;
        lo[j] = f2bf_bits(f - fh);
    }
}
__device__ __forceinline__ void zero8(short8& hi, short8& lo) {
#pragma unroll
    for (int j = 0; j < 8; j++) { hi[j] = 0; lo[j] = 0; }
}

#define MFMA(a, b, c) __builtin_amdgcn_mfma_f32_16x16x32_bf16(a, b, c, 0, 0, 0)

// ---------------- weight fragment prep (once per call; shared by all waves) ----
// msg fragments: per round, 16 slots (tile 0..7 x ks 0..1); hi block then lo.
__global__ __launch_bounds__(64) void prep_msg(
    const float* __restrict__ msg_W, short* __restrict__ frag)
{
    const int slot = blockIdx.x & 15, t = blockIdx.x >> 4, lane = threadIdx.x;
    const int tile = slot >> 1, ks = slot & 1;
    const float* W = msg_W + (size_t)t * H * 129;
    const int wrow = (tile & 3) * 16 + (lane & 15);
    const int coff = (tile < 4) ? 0 : 64;
    const int kq = (lane >> 4) * 8;
    short8 hi, lo;
    split8(W + (size_t)wrow * 129 + coff + ks * 32 + kq, hi, lo);
    short8* out = (short8*)(frag + (size_t)t * 16384);
    out[slot * 64 + lane] = hi;
    out[16 * 64 + slot * 64 + lane] = lo;
}

// gru fragments: per round, 48 slots (tile 0..23 x ks 0..1); hi block then lo.
__global__ __launch_bounds__(64) void prep_gru(
    const float* __restrict__ Wih, const float* __restrict__ Whh,
    short* __restrict__ frag)
{
    const int slot = blockIdx.x % 48, t = blockIdx.x / 48, lane = threadIdx.x;
    const int tile = slot >> 1, ks = slot & 1;
    const int kq = (lane >> 4) * 8;
    const float* Wp = (tile < 12)
        ? (Wih + (size_t)t * 192 * H + ((size_t)(tile * 16 + (lane & 15))) * H)
        : (Whh + (size_t)t * 192 * H + ((size_t)((tile - 12) * 16 + (lane & 15))) * H);
    short8 hi, lo;
    split8(Wp + ks * 32 + kq, hi, lo);
    short8* out = (short8*)(frag + (size_t)t * 49152);
    out[slot * 64 + lane] = hi;
    out[48 * 64 + slot * 64 + lane] = lo;
}

// ---------------- count: deg[n] += 1, record local position --------------------
__global__ __launch_bounds__(256) void count_kernel(
    const int* __restrict__ row, int* __restrict__ deg,
    int* __restrict__ lpos, int E)
{
    int e = blockIdx.x * 256 + threadIdx.x;
    if (e < E) lpos[e] = atomicAdd(&deg[row[e]], 1);
}

// ---------------- 3-phase exclusive scan of deg -> offsets ---------------------
__global__ __launch_bounds__(256) void scan_block(
    const int* __restrict__ deg, int* __restrict__ offsets,
    int* __restrict__ block_sums, int N)
{
    __shared__ int s[256];
    int tid = threadIdx.x, gid = blockIdx.x * 256 + tid;
    int v = (gid < N) ? deg[gid] : 0;
    s[tid] = v; __syncthreads();
    for (int off = 1; off < 256; off <<= 1) {
        int t = (tid >= off) ? s[tid - off] : 0;
        __syncthreads();
        s[tid] += t;
        __syncthreads();
    }
    if (gid < N) offsets[gid] = s[tid] - v;   // exclusive
    if (tid == 255) block_sums[blockIdx.x] = s[255];
}

__global__ __launch_bounds__(512) void scan_sums(int* __restrict__ block_sums, int nb)
{
    __shared__ int s[512];
    int tid = threadIdx.x;
    int v = (tid < nb) ? block_sums[tid] : 0;
    s[tid] = v; __syncthreads();
    for (int off = 1; off < 512; off <<= 1) {
        int t = (tid >= off) ? s[tid - off] : 0;
        __syncthreads();
        s[tid] += t;
        __syncthreads();
    }
    if (tid < nb) block_sums[tid] = s[tid] - v;  // exclusive
}

__global__ __launch_bounds__(256) void scan_add(
    int* __restrict__ offsets, const int* __restrict__ block_sums, int N, int E)
{
    int gid = blockIdx.x * 256 + threadIdx.x;
    if (gid < N) offsets[gid] += block_sums[blockIdx.x];
    if (gid == 0) offsets[N] = E;
}

// ---------------- atomic-free CSR scatter --------------------------------------
__global__ __launch_bounds__(256) void scatter_kernel(
    const int* __restrict__ row, const int* __restrict__ col,
    const float* __restrict__ attr, const int* __restrict__ offsets,
    const int* __restrict__ lpos,
    int* __restrict__ col_sorted, float* __restrict__ attr_sorted, int E)
{
    int e = blockIdx.x * 256 + threadIdx.x;
    if (e < E) {
        int p = offsets[row[e]] + lpos[e];
        col_sorted[p] = col[e];
        attr_sorted[p] = attr[e];
    }
}

// ---------------- node transform (MFMA, pre-split weights) ---------------------
// xd[n] = Wd*x_n (tiles 0..3); agg[n] = deg*(Ws*x_n + b) (tiles 4..7)
__global__ __launch_bounds__(256) void node_transform_mfma(
    const float* __restrict__ x, const short* __restrict__ frag,
    const float* __restrict__ b, const int* __restrict__ deg,
    float* __restrict__ xd, float* __restrict__ agg, int N)
{
    const int tid = threadIdx.x, lane = tid & 63, wv = tid >> 6;
    const int base = (blockIdx.x * 4 + wv) * 16;
    const int mrow = base + (lane & 15);
    const int kq = (lane >> 4) * 8;
    const short8* fhi = (const short8*)frag;
    const short8* flo = fhi + 16 * 64;

    short8 ah[2], al[2];
#pragma unroll
    for (int ks = 0; ks < 2; ks++) {
        if (mrow < N) split8(x + (size_t)mrow * H + ks * 32 + kq, ah[ks], al[ks]);
        else          zero8(ah[ks], al[ks]);
    }

    float4v acc[8];
#pragma unroll
    for (int t = 0; t < 8; t++) acc[t] = (float4v){0.f, 0.f, 0.f, 0.f};

#pragma unroll
    for (int t = 0; t < 8; t++) {
#pragma unroll
        for (int ks = 0; ks < 2; ks++) {
            const int slot = t * 2 + ks;
            short8 bh = fhi[slot * 64 + lane];
            short8 bl = flo[slot * 64 + lane];
            acc[t] = MFMA(ah[ks], bh, acc[t]);
            acc[t] = MFMA(al[ks], bh, acc[t]);
            acc[t] = MFMA(ah[ks], bl, acc[t]);
        }
    }

    const int colb = lane & 15;
    const int rquad = (lane >> 4) * 4;
#pragma unroll
    for (int r = 0; r < 4; r++) {
        const int m = base + rquad + r;
        if (m >= N) continue;
        const float dg = (float)deg[m];
#pragma unroll
        for (int t = 0; t < 4; t++) {
            const int col = t * 16 + colb;
            xd[(size_t)m * H + col] = acc[t][r];
            agg[(size_t)m * H + col] = dg * (acc[4 + t][r] + b[col]);
        }
    }
}

// ---------------- gather aggregation (fp32 xd, 4-way ILP) -----------------------
// agg[n][j] += sum_e ( xd[col_e][j] + wa[j]*attr_e )
__global__ __launch_bounds__(256) void aggregate(
    const int* __restrict__ offsets, const int* __restrict__ col_sorted,
    const float* __restrict__ attr_sorted, const float* __restrict__ xd,
    const float* __restrict__ W, float* __restrict__ agg, int N)
{
    const int tid = threadIdx.x, lane = tid & 63, wv = tid >> 6;
    const int n = blockIdx.x * 4 + wv;
    if (n >= N) return;
    const float wa = W[(size_t)lane * 129 + 128];
    const int beg = offsets[n], end = offsets[n + 1];
    float acc0 = agg[(size_t)n * H + lane];
    float acc1 = 0.f, acc2 = 0.f, acc3 = 0.f;
    for (int k = beg; k < end; k += 64) {
        int cnt = end - k; if (cnt > 64) cnt = 64;
        int cl = 0; float al = 0.f;
        if (k + lane < end) {
            cl = col_sorted[k + lane];
            al = attr_sorted[k + lane];
        }
        int j = 0;
        for (; j + 4 <= cnt; j += 4) {
            int c0 = __builtin_amdgcn_readlane(cl, j);
            int c1 = __builtin_amdgcn_readlane(cl, j + 1);
            int c2 = __builtin_amdgcn_readlane(cl, j + 2);
            int c3 = __builtin_amdgcn_readlane(cl, j + 3);
            float a0 = lane_bcast(al, j);
            float a1 = lane_bcast(al, j + 1);
            float a2 = lane_bcast(al, j + 2);
            float a3 = lane_bcast(al, j + 3);
            float v0 = xd[(size_t)c0 * H + lane];
            float v1 = xd[(size_t)c1 * H + lane];
            float v2 = xd[(size_t)c2 * H + lane];
            float v3 = xd[(size_t)c3 * H + lane];
            acc0 += fmaf(wa, a0, v0);
            acc1 += fmaf(wa, a1, v1);
            acc2 += fmaf(wa, a2, v2);
            acc3 += fmaf(wa, a3, v3);
        }
        for (; j < cnt; j++) {
            int c = __builtin_amdgcn_readlane(cl, j);
            float a = lane_bcast(al, j);
            acc0 += fmaf(wa, a, xd[(size_t)c * H + lane]);
        }
    }
    agg[(size_t)n * H + lane] = (acc0 + acc1) + (acc2 + acc3);
}

// ---------------- GRU cell (MFMA, pre-split weights) ----------------------------
__global__ __launch_bounds__(256) void gru_mfma(
    const float* __restrict__ agg, float* __restrict__ x,
    const short* __restrict__ frag,
    const float* __restrict__ bih, const float* __restrict__ bhh, int N)
{
    const int tid = threadIdx.x, lane = tid & 63, wv = tid >> 6;
    const int base = (blockIdx.x * 4 + wv) * 16;
    const int mrow = base + (lane & 15);
    const int kq = (lane >> 4) * 8;
    const short8* fhi = (const short8*)frag;
    const short8* flo = fhi + 48 * 64;

    short8 gah[2], gal[2], hh[2], hl[2];
#pragma unroll
    for (int ks = 0; ks < 2; ks++) {
        if (mrow < N) {
            split8(agg + (size_t)mrow * H + ks * 32 + kq, gah[ks], gal[ks]);
            split8(x   + (size_t)mrow * H + ks * 32 + kq, hh[ks],  hl[ks]);
        } else { zero8(gah[ks], gal[ks]); zero8(hh[ks], hl[ks]); }
    }

    float4v acc[24];
#pragma unroll
    for (int t = 0; t < 24; t++) acc[t] = (float4v){0.f, 0.f, 0.f, 0.f};

#pragma unroll
    for (int t = 0; t < 24; t++) {
#pragma unroll
        for (int ks = 0; ks < 2; ks++) {
            const int slot = t * 2 + ks;
            short8 bh = fhi[slot * 64 + lane];
            short8 bl = flo[slot * 64 + lane];
            if (t < 12) {
                acc[t] = MFMA(gah[ks], bh, acc[t]);
                acc[t] = MFMA(gal[ks], bh, acc[t]);
                acc[t] = MFMA(gah[ks], bl, acc[t]);
            } else {
                acc[t] = MFMA(hh[ks], bh, acc[t]);
                acc[t] = MFMA(hl[ks], bh, acc[t]);
                acc[t] = MFMA(hh[ks], bl, acc[t]);
            }
        }
    }

    const int colb = lane & 15;
    const int rquad = (lane >> 4) * 4;
#pragma unroll
    for (int j4 = 0; j4 < 4; j4++) {
        const int j = j4 * 16 + colb;
        const float b_ir = bih[j],       b_hr = bhh[j];
        const float b_iz = bih[64 + j],  b_hz = bhh[64 + j];
        const float b_in = bih[128 + j], b_hn = bhh[128 + j];
#pragma unroll
        for (int r = 0; r < 4; r++) {
            const int m = base + rquad + r;
            if (m >= N) continue;
            float ir = acc[j4][r]      + b_ir;
            float hr = acc[12 + j4][r] + b_hr;
            float iz = acc[4 + j4][r]  + b_iz;
            float hz = acc[16 + j4][r] + b_hz;
            float in_ = acc[8 + j4][r]  + b_in;
            float hn  = acc[20 + j4][r] + b_hn;
            float rr = 1.f / (1.f + __expf(-(ir + hr)));
            float zz = 1.f / (1.f + __expf(-(iz + hz)));
            float e2 = __expf(2.f * (in_ + rr * hn));
            float nn = 1.f - 2.f / (e2 + 1.f);          // tanh
            float hold = x[(size_t)m * H + j];
            x[(size_t)m * H + j] = (1.f - zz) * nn + zz * hold;
        }
    }
}

extern "C" void kernel_launch(void* const* d_in, const int* in_sizes, int n_in,
                              void* d_out, int out_size, void* d_ws, size_t ws_size,
                              hipStream_t stream) {
    const float* x_in  = (const float*)d_in[0];
    const int*   ei    = (const int*)d_in[1];
    const float* attr  = (const float*)d_in[2];
    const float* msg_W = (const float*)d_in[3];
    const float* msg_b = (const float*)d_in[4];
    const float* Wih   = (const float*)d_in[5];
    const float* bih   = (const float*)d_in[6];
    const float* Whh   = (const float*)d_in[7];
    const float* bhh   = (const float*)d_in[8];

    const int N = in_sizes[0] / H;        // 100000
    const int E = in_sizes[2];            // 1250000
    const int T = in_sizes[4] / H;        // 2
    const int* row = ei;
    const int* col = ei + E;

    // ---- workspace layout ----
    float* x          = (float*)d_out;                    // live node state [N,H]
    float* agg        = (float*)d_ws;                     // [N,H]
    float* xd         = agg + (size_t)N * H;              // [N,H]
    int*   deg        = (int*)(xd + (size_t)N * H);       // [N]
    int*   offsets    = deg + N;                          // [N+1]
    int*   bsums      = offsets + (N + 1);                // [512]
    int*   lpos       = bsums + 512;                      // [E]
    int*   col_sorted = lpos + E;                         // [E]
    float* attr_sorted = (float*)(col_sorted + E);        // [E]
    short* msgfrag    = (short*)(attr_sorted + E);        // [T][16384]
    short* grufrag    = msgfrag + (size_t)T * 16384;      // [T][49152]

    const int nb = (N + 255) / 256;
    const int eb = (E + 255) / 256;

    hipMemcpyAsync(x, x_in, (size_t)N * H * sizeof(float),
                   hipMemcpyDeviceToDevice, stream);
    hipMemsetAsync(deg, 0, (size_t)N * sizeof(int), stream);

    prep_msg<<<T * 16, 64, 0, stream>>>(msg_W, msgfrag);
    prep_gru<<<T * 48, 64, 0, stream>>>(Wih, Whh, grufrag);

    count_kernel<<<eb, 256, 0, stream>>>(row, deg, lpos, E);
    scan_block<<<nb, 256, 0, stream>>>(deg, offsets, bsums, N);
    scan_sums<<<1, 512, 0, stream>>>(bsums, nb);
    scan_add<<<nb, 256, 0, stream>>>(offsets, bsums, N, E);
    scatter_kernel<<<eb, 256, 0, stream>>>(row, col, attr, offsets, lpos,
                                           col_sorted, attr_sorted, E);

    const int nb64 = (N + 63) / 64;          // 64 nodes / 256-thread block
    const int agg_blocks = (N + 3) / 4;      // 4 nodes (waves) / block

    for (int t = 0; t < T; t++) {
        const float* Wt = msg_W + (size_t)t * H * (2 * H + 1);
        node_transform_mfma<<<nb64, 256, 0, stream>>>(
            x, msgfrag + (size_t)t * 16384, msg_b + (size_t)t * H, deg, xd, agg, N);
        aggregate<<<agg_blocks, 256, 0, stream>>>(
            offsets, col_sorted, attr_sorted, xd, Wt, agg, N);
        gru_mfma<<<nb64, 256, 0, stream>>>(
            agg, x, grufrag + (size_t)t * 49152,
            bih + (size_t)t * 3 * H, bhh + (size_t)t * 3 * H, N);
    }
}